// Round 7
// baseline (573.849 us; speedup 1.0000x reference)
//
#include <hip/hip_runtime.h>
#include <math.h>

typedef unsigned short ushort_t;
typedef unsigned int uint_t;
typedef __attribute__((ext_vector_type(8))) short short8;
typedef __attribute__((ext_vector_type(4))) float floatx4;

// Problem dims
constexpr int B = 8;
constexpr int S = 2048;
constexpr int D = 512;
constexpr int BS = B * S;          // 16384 rows
constexpr float LN_EPS = 1e-5f;
constexpr float ATTN_SCALE = 0.04419417382415922f;  // 1/sqrt(512)

// R5 lesson: global_load_lds on this toolchain = 0 speedup + post-warm
// corruption -> stick to padded-LDS VGPR staging.
// R6 lesson: tile-shape alone didn't move MfmaUtil (10%); the K-loop is
// latency-exposed (loads issued then immediately vmcnt-waited at LDS write).
// R7: software-pipelined K-loop — prefetch k+1 into VGPRs during MFMA of k.

// ---------------------------------------------------------------------------
// bf16 helpers (RNE)
// ---------------------------------------------------------------------------
__device__ __forceinline__ ushort_t f2bf(float f) {
    union { float f; uint_t u; } x; x.f = f;
    uint_t r = x.u + 0x7fffu + ((x.u >> 16) & 1u);
    return (ushort_t)(r >> 16);
}
__device__ __forceinline__ float bf2f(ushort_t h) {
    union { uint_t u; float f; } y; y.u = ((uint_t)h) << 16;
    return y.f;
}
__device__ __forceinline__ short8 pack8(float4 a, float4 b) {
    short8 p;
    p[0] = (short)f2bf(a.x); p[1] = (short)f2bf(a.y);
    p[2] = (short)f2bf(a.z); p[3] = (short)f2bf(a.w);
    p[4] = (short)f2bf(b.x); p[5] = (short)f2bf(b.y);
    p[6] = (short)f2bf(b.z); p[7] = (short)f2bf(b.w);
    return p;
}

// ---------------------------------------------------------------------------
// Reductions (256-thread blocks = 4 waves of 64)
// ---------------------------------------------------------------------------
__device__ __forceinline__ float blk_reduce_sum(float v, float* sm) {
#pragma unroll
    for (int o = 32; o; o >>= 1) v += __shfl_down(v, o, 64);
    __syncthreads();
    if ((threadIdx.x & 63) == 0) sm[threadIdx.x >> 6] = v;
    __syncthreads();
    return sm[0] + sm[1] + sm[2] + sm[3];
}
__device__ __forceinline__ float blk_reduce_max(float v, float* sm) {
#pragma unroll
    for (int o = 32; o; o >>= 1) v = fmaxf(v, __shfl_down(v, o, 64));
    __syncthreads();
    if ((threadIdx.x & 63) == 0) sm[threadIdx.x >> 6] = v;
    __syncthreads();
    return fmaxf(fmaxf(sm[0], sm[1]), fmaxf(sm[2], sm[3]));
}

// ---------------------------------------------------------------------------
// fp32 [R][C] -> bf16 [C][R] transpose+convert; batched via blockIdx.z (z*R*C)
// ---------------------------------------------------------------------------
__global__ __launch_bounds__(256) void transpose_cvt(
    const float* __restrict__ in, ushort_t* __restrict__ out, int R, int C) {
    __shared__ float tl[32][33];
    const size_t zoff = (size_t)blockIdx.z * R * C;
    const int tx = threadIdx.x & 31, ty = threadIdx.x >> 5;  // ty 0..7
    const int c0 = blockIdx.x * 32, r0 = blockIdx.y * 32;
#pragma unroll
    for (int i = 0; i < 4; i++)
        tl[ty + i * 8][tx] = in[zoff + (size_t)(r0 + ty + i * 8) * C + c0 + tx];
    __syncthreads();
#pragma unroll
    for (int i = 0; i < 4; i++)
        out[zoff + (size_t)(c0 + ty + i * 8) * R + r0 + tx] = f2bf(tl[tx][ty + i * 8]);
}

// ---------------------------------------------------------------------------
// Pipelined MFMA GEMM core (128x64 tile, BK=32, 256 threads).
// LDS: As 128x40, Bs 64x40 ushort (padded, conflict-light) = 15,360 B.
// Wave w -> 32x64 tile: acc 2x4 of 16x16x32 mfma (32 VGPR).
// K-loop: sync / write(cur) / sync / prefetch(k+1) / mfma(cur).
// ---------------------------------------------------------------------------
#define GEMM3_PREAMBLE()                                                       \
    __shared__ ushort_t As[128 * 40];                                          \
    __shared__ ushort_t Bs[64 * 40];                                           \
    const int t = threadIdx.x;                                                 \
    const int m0 = blockIdx.y * 128, n0 = blockIdx.x * 64;                     \
    const int sr = t >> 2;               /* 0..63 */                           \
    const int sc = (t & 3) * 8;          /* 0,8,16,24 */                       \
    const int lane = t & 63, w = t >> 6;                                       \
    const int wm = w * 32;                                                     \
    const int fr = lane & 15, fq = lane >> 4;                                  \
    floatx4 acc[2][4];                                                         \
    _Pragma("unroll") for (int i = 0; i < 2; i++)                              \
        _Pragma("unroll") for (int j = 0; j < 4; j++) {                        \
            acc[i][j][0] = 0.f; acc[i][j][1] = 0.f;                            \
            acc[i][j][2] = 0.f; acc[i][j][3] = 0.f; }

#define GEMM3_MFMA_STAGE()                                                     \
    {                                                                          \
        short8 af[2], bfg[4];                                                  \
        _Pragma("unroll") for (int i = 0; i < 2; i++)                          \
            af[i]  = *(const short8*)&As[(wm + i * 16 + fr) * 40 + fq * 8];    \
        _Pragma("unroll") for (int j = 0; j < 4; j++)                          \
            bfg[j] = *(const short8*)&Bs[(j * 16 + fr) * 40 + fq * 8];         \
        _Pragma("unroll") for (int i = 0; i < 2; i++)                          \
            _Pragma("unroll") for (int j = 0; j < 4; j++)                      \
                acc[i][j] = __builtin_amdgcn_mfma_f32_16x16x32_bf16(           \
                    af[i], bfg[j], acc[i][j], 0, 0, 0);                        \
    }

// EPI: 0 = scale + bf16 store; 1 = +bias, exact gelu, bf16 store;
//      2 = fp32 accumulate in place (T += acc [+ bias if init])
template <int EPI>
__global__ __launch_bounds__(256) void gemm3p_std(
    const ushort_t* __restrict__ A, int lda, long sAz,
    const ushort_t* __restrict__ Bt, int ldb, long sBz,
    void* __restrict__ Cv, int ldc, long sCz,
    int K, const float* __restrict__ bias, float scale, int init) {
    GEMM3_PREAMBLE();
    const ushort_t* Ab = A + (size_t)blockIdx.z * sAz + (size_t)m0 * lda;
    const ushort_t* Bb = Bt + (size_t)blockIdx.z * sBz + (size_t)n0 * ldb;

    // preload k=0
    int4 ra0 = *(const int4*)(Ab + (size_t)sr * lda + sc);
    int4 ra1 = *(const int4*)(Ab + (size_t)(sr + 64) * lda + sc);
    int4 rb0 = *(const int4*)(Bb + (size_t)sr * ldb + sc);

    for (int k0 = 0; k0 < K; k0 += 32) {
        __syncthreads();                     // LDS of prev iter fully consumed
        *(int4*)&As[sr * 40 + sc] = ra0;
        *(int4*)&As[(sr + 64) * 40 + sc] = ra1;
        *(int4*)&Bs[sr * 40 + sc] = rb0;
        __syncthreads();
        if (k0 + 32 < K) {                   // prefetch next tile (in flight
            const int kn = k0 + 32 + sc;     //  during MFMA + next barrier)
            ra0 = *(const int4*)(Ab + (size_t)sr * lda + kn);
            ra1 = *(const int4*)(Ab + (size_t)(sr + 64) * lda + kn);
            rb0 = *(const int4*)(Bb + (size_t)sr * ldb + kn);
        }
        GEMM3_MFMA_STAGE();
    }

#pragma unroll
    for (int i = 0; i < 2; i++) {
#pragma unroll
        for (int j = 0; j < 4; j++) {
#pragma unroll
            for (int r = 0; r < 4; r++) {
                const int m = m0 + wm + i * 16 + fq * 4 + r;
                const int n = n0 + j * 16 + fr;
                float v = acc[i][j][r];
                if (EPI == 0) {
                    ushort_t* C = (ushort_t*)Cv + (size_t)blockIdx.z * sCz;
                    C[(size_t)m * ldc + n] = f2bf(v * scale);
                } else if (EPI == 1) {
                    const float x = v + bias[n];
                    const float gl = 0.5f * x * (1.f + erff(x * 0.70710678118654752f));
                    ushort_t* C = (ushort_t*)Cv;
                    C[(size_t)m * ldc + n] = f2bf(gl);
                } else {
                    float* T = (float*)Cv;
                    const size_t idx = (size_t)m * ldc + n;
                    T[idx] = T[idx] + v + (init ? bias[n] : 0.f);
                }
            }
        }
    }
}

// Gate GEMM (pipelined, BN=64): A = concat(NX,CD) fp32 (convert at LDS-write),
// B = WgT bf16 [512][1024].  Epilogue: g = sigmoid(acc+bg); Fb = g*NX+(1-g)*CD.
__global__ __launch_bounds__(256) void gate_gemmp(
    const float* __restrict__ NX, const float* __restrict__ CD,
    const ushort_t* __restrict__ WgT, const float* __restrict__ bg,
    ushort_t* __restrict__ Fb) {
    GEMM3_PREAMBLE();
    const ushort_t* Bb = WgT + (size_t)n0 * 1024;

    // preload k=0 (Asrc = NX)
    float4 f00 = *(const float4*)(NX + (size_t)(m0 + sr) * 512 + sc);
    float4 f01 = *(const float4*)(NX + (size_t)(m0 + sr) * 512 + sc + 4);
    float4 f10 = *(const float4*)(NX + (size_t)(m0 + sr + 64) * 512 + sc);
    float4 f11 = *(const float4*)(NX + (size_t)(m0 + sr + 64) * 512 + sc + 4);
    int4 rb0 = *(const int4*)(Bb + (size_t)sr * 1024 + sc);

    for (int k0 = 0; k0 < 1024; k0 += 32) {
        __syncthreads();
        *(short8*)&As[sr * 40 + sc] = pack8(f00, f01);
        *(short8*)&As[(sr + 64) * 40 + sc] = pack8(f10, f11);
        *(int4*)&Bs[sr * 40 + sc] = rb0;
        __syncthreads();
        if (k0 + 32 < 1024) {
            const int k1 = k0 + 32;
            const float* Asrc = (k1 < 512) ? NX : CD;
            const int kk = (k1 & 511) + sc;
            f00 = *(const float4*)(Asrc + (size_t)(m0 + sr) * 512 + kk);
            f01 = *(const float4*)(Asrc + (size_t)(m0 + sr) * 512 + kk + 4);
            f10 = *(const float4*)(Asrc + (size_t)(m0 + sr + 64) * 512 + kk);
            f11 = *(const float4*)(Asrc + (size_t)(m0 + sr + 64) * 512 + kk + 4);
            rb0 = *(const int4*)(Bb + (size_t)sr * 1024 + k1 + sc);
        }
        GEMM3_MFMA_STAGE();
    }

#pragma unroll
    for (int i = 0; i < 2; i++) {
#pragma unroll
        for (int j = 0; j < 4; j++) {
#pragma unroll
            for (int r = 0; r < 4; r++) {
                const int m = m0 + wm + i * 16 + fq * 4 + r;
                const int n = n0 + j * 16 + fr;
                const float z = acc[i][j][r] + bg[n];
                const float g = 1.f / (1.f + expf(-z));
                const size_t idx = (size_t)m * 512 + n;
                Fb[idx] = f2bf(g * NX[idx] + (1.f - g) * CD[idx]);
            }
        }
    }
}

// QK GEMM (pipelined, BN=64): Sc[z] = (Q[z] @ X[z]^T) * scale.
// A = Fb bf16 [seq][512]; B = X fp32 rows [seq][512] (natural [n][k]),
// converted at LDS-write.
__global__ __launch_bounds__(256) void qk_gemmp(
    const ushort_t* __restrict__ Qb, const float* __restrict__ Xf,
    ushort_t* __restrict__ Sc) {
    GEMM3_PREAMBLE();
    const ushort_t* Ab = Qb + (size_t)blockIdx.z * S * D + (size_t)m0 * D;
    const float*    Bf = Xf + (size_t)blockIdx.z * S * D + (size_t)n0 * D;
    ushort_t* Scb = Sc + (size_t)blockIdx.z * S * S;

    int4 ra0 = *(const int4*)(Ab + (size_t)sr * D + sc);
    int4 ra1 = *(const int4*)(Ab + (size_t)(sr + 64) * D + sc);
    float4 g0 = *(const float4*)(Bf + (size_t)sr * D + sc);
    float4 g1 = *(const float4*)(Bf + (size_t)sr * D + sc + 4);

    for (int k0 = 0; k0 < D; k0 += 32) {
        __syncthreads();
        *(int4*)&As[sr * 40 + sc] = ra0;
        *(int4*)&As[(sr + 64) * 40 + sc] = ra1;
        *(short8*)&Bs[sr * 40 + sc] = pack8(g0, g1);
        __syncthreads();
        if (k0 + 32 < D) {
            const int kn = k0 + 32 + sc;
            ra0 = *(const int4*)(Ab + (size_t)sr * D + kn);
            ra1 = *(const int4*)(Ab + (size_t)(sr + 64) * D + kn);
            g0 = *(const float4*)(Bf + (size_t)sr * D + kn);
            g1 = *(const float4*)(Bf + (size_t)sr * D + kn + 4);
        }
        GEMM3_MFMA_STAGE();
    }

#pragma unroll
    for (int i = 0; i < 2; i++) {
#pragma unroll
        for (int j = 0; j < 4; j++) {
#pragma unroll
            for (int r = 0; r < 4; r++) {
                const int m = m0 + wm + i * 16 + fq * 4 + r;
                const int n = n0 + j * 16 + fr;
                Scb[(size_t)m * S + n] = f2bf(acc[i][j][r] * ATTN_SCALE);
            }
        }
    }
}

// ---------------------------------------------------------------------------
// Softmax over bf16 rows of 2048, in place
// ---------------------------------------------------------------------------
__global__ __launch_bounds__(256) void softmax_bf16(ushort_t* __restrict__ Sc) {
    __shared__ float sm[4];
    ushort_t* row = Sc + (size_t)blockIdx.x * 2048;
    const int t = threadIdx.x;
    ushort_t raw[8];
    *(int4*)raw = *(const int4*)(row + t * 8);
    float e[8];
    float mx = -1e30f;
#pragma unroll
    for (int j = 0; j < 8; j++) { e[j] = bf2f(raw[j]); mx = fmaxf(mx, e[j]); }
    mx = blk_reduce_max(mx, sm);
    float s = 0.f;
#pragma unroll
    for (int j = 0; j < 8; j++) { e[j] = expf(e[j] - mx); s += e[j]; }
    s = blk_reduce_sum(s, sm);
    const float inv = 1.f / s;
#pragma unroll
    for (int j = 0; j < 8; j++) raw[j] = f2bf(e[j] * inv);
    *(int4*)(row + t * 8) = *(const int4*)raw;
}

// ---------------------------------------------------------------------------
// LN1: q = LN(fused + attn) -> qf (fp32) and qb (bf16)
// ---------------------------------------------------------------------------
__global__ __launch_bounds__(256) void ln1_kernel(
    const ushort_t* __restrict__ Fb, const ushort_t* __restrict__ Ab,
    const float* __restrict__ g1, const float* __restrict__ be1,
    float* __restrict__ qf, ushort_t* __restrict__ qb) {
    __shared__ float sm[4];
    const size_t base = (size_t)blockIdx.x * 512;
    const int t = threadIdx.x;
    const float v0 = bf2f(Fb[base + t]) + bf2f(Ab[base + t]);
    const float v1 = bf2f(Fb[base + t + 256]) + bf2f(Ab[base + t + 256]);
    const float mu = blk_reduce_sum(v0 + v1, sm) * (1.f / 512.f);
    const float d0 = v0 - mu, d1 = v1 - mu;
    const float var = blk_reduce_sum(d0 * d0 + d1 * d1, sm) * (1.f / 512.f);
    const float rs = rsqrtf(var + LN_EPS);
    const float y0 = d0 * rs * g1[t] + be1[t];
    const float y1 = d1 * rs * g1[t + 256] + be1[t + 256];
    qf[base + t] = y0;          qf[base + t + 256] = y1;
    qb[base + t] = f2bf(y0);    qb[base + t + 256] = f2bf(y1);
}

// Final LN in place on fp32
__global__ __launch_bounds__(256) void ln2_kernel(
    float* __restrict__ T, const float* __restrict__ g,
    const float* __restrict__ be) {
    __shared__ float sm[4];
    const size_t base = (size_t)blockIdx.x * 512;
    const int t = threadIdx.x;
    const float v0 = T[base + t];
    const float v1 = T[base + t + 256];
    const float mu = blk_reduce_sum(v0 + v1, sm) * (1.f / 512.f);
    const float d0 = v0 - mu, d1 = v1 - mu;
    const float var = blk_reduce_sum(d0 * d0 + d1 * d1, sm) * (1.f / 512.f);
    const float rs = rsqrtf(var + LN_EPS);
    T[base + t] = d0 * rs * g[t] + be[t];
    T[base + t + 256] = d1 * rs * g[t + 256] + be[t + 256];
}

// ---------------------------------------------------------------------------
extern "C" void kernel_launch(void* const* d_in, const int* in_sizes, int n_in,
                              void* d_out, int out_size, void* d_ws, size_t ws_size,
                              hipStream_t stream) {
    const float* NX  = (const float*)d_in[0];
    const float* X   = (const float*)d_in[1];
    const float* CD  = (const float*)d_in[2];
    const float* Wg  = (const float*)d_in[3];
    const float* bg  = (const float*)d_in[4];
    const float* W1  = (const float*)d_in[5];
    const float* b1  = (const float*)d_in[6];
    const float* W2  = (const float*)d_in[7];
    const float* b2  = (const float*)d_in[8];
    const float* g1  = (const float*)d_in[9];
    const float* be1 = (const float*)d_in[10];
    const float* g2  = (const float*)d_in[11];
    const float* be2 = (const float*)d_in[12];

    // ws: 3 slots x 16,777,216 B = 50,331,648 B (proven-safe since R2)
    // slot0: attnb -> hbuf;  slot1: Fb -> W1T/W2T;  slot2: WgT -> XbT -> qb
    // d_out: scores (bf16) -> qf (fp32, final)
    ushort_t* slot0 = (ushort_t*)d_ws;
    ushort_t* slot1 = (ushort_t*)((char*)d_ws + 16777216);
    ushort_t* slot2 = (ushort_t*)((char*)d_ws + 33554432);
    ushort_t* attnb = slot0;
    ushort_t* hbuf  = slot0;
    ushort_t* Fb    = slot1;
    ushort_t* W1T   = slot1;                    // [1024][512] bf16, 1 MB
    ushort_t* W2T   = slot1 + 524288;           // [512][1024] bf16, 1 MB
    ushort_t* WgT   = slot2;                    // [512][1024] bf16, 1 MB
    ushort_t* XbT   = slot2;                    // [8][512][2048] bf16, 16.78 MB
    ushort_t* qb    = slot2;                    // [BS][512] bf16
    ushort_t* Scb   = (ushort_t*)d_out;         // 4 batches [S][S] bf16
    float*    qf    = (float*)d_out;

    // 1) Wg^T (slot2)
    transpose_cvt<<<dim3(512 / 32, 1024 / 32, 1), 256, 0, stream>>>(Wg, WgT, 1024, 512);

    // 2) gated fusion -> Fb (pipelined, grid 1024)
    gate_gemmp<<<dim3(8, 128), 256, 0, stream>>>(NX, CD, WgT, bg, Fb);

    // 3) X^T per batch into slot2 (WgT dead) — needed by PV
    transpose_cvt<<<dim3(512 / 32, 2048 / 32, 8), 256, 0, stream>>>(X, XbT, 2048, 512);

    // 4) attention in 2 groups of 4 batches; scores in d_out
    for (int g = 0; g < 2; g++) {
        const size_t go = (size_t)g * 4 * S * 512;
        qk_gemmp<<<dim3(32, 16, 4), 256, 0, stream>>>(Fb + go, X + go, Scb);
        softmax_bf16<<<4 * S, 256, 0, stream>>>(Scb);
        gemm3p_std<0><<<dim3(8, 16, 4), 256, 0, stream>>>(
            Scb, S, (long)S * S,                // A = P [2048][2048]
            XbT + go, S, (long)D * S,           // Bt = X^T [512][2048]
            (void*)(attnb + go), 512, (long)S * 512, S, nullptr, 1.f, 0);
    }

    // 5) q = LN(fused + attn): qf -> d_out (scores dead), qb -> slot2 (XbT dead)
    ln1_kernel<<<BS, 256, 0, stream>>>(Fb, attnb, g1, be1, qf, qb);

    // 6) weight transposes into slot1 (Fb dead after LN1)
    transpose_cvt<<<dim3(1024 / 32, 512 / 32, 1), 256, 0, stream>>>(W1, W1T, 512, 1024);
    transpose_cvt<<<dim3(512 / 32, 1024 / 32, 1), 256, 0, stream>>>(W2, W2T, 1024, 512);

    // 7) FFN in 2 halves; hidden half in slot0 (attnb dead); t accumulates in d_out
    for (int h = 0; h < 2; h++) {
        gemm3p_std<1><<<dim3(8, 128), 256, 0, stream>>>(
            qb, 512, 0, W1T + (size_t)h * 512 * 512, 512, 0,
            (void*)hbuf, 512, 0, 512, b1 + h * 512, 1.f, 0);
        gemm3p_std<2><<<dim3(8, 128), 256, 0, stream>>>(
            hbuf, 512, 0, W2T + h * 512, 1024, 0,
            (void*)qf, 512, 0, 512, b2, 1.f, h == 0 ? 1 : 0);
    }

    // 8) out = LN(t) in place in d_out
    ln2_kernel<<<BS, 256, 0, stream>>>(qf, g2, be2);
}